// Round 1
// baseline (1694.678 us; speedup 1.0000x reference)
//
#include <hip/hip_runtime.h>
#include <math.h>

#define DI __device__ __forceinline__

constexpr int BB = 64;     // batch
constexpr int TT = 128;    // actions time steps (obs/rewards have TT+1)
constexpr int SS = 512;    // states
constexpr int AA = 16;     // actions
constexpr int OO = 4096;   // observations
constexpr float LOG2PI = 1.8378770664093453f;

// ---------------- reduction helpers (wave64) ----------------
DI float bflyMax(float v) {
#pragma unroll
    for (int off = 32; off; off >>= 1) v = fmaxf(v, __shfl_xor(v, off));
    return v;
}
DI float bflySum(float v) {
#pragma unroll
    for (int off = 32; off; off >>= 1) v += __shfl_xor(v, off);
    return v;
}

template <int NW>
DI float blockMax(float v, float* wr) {
    v = bflyMax(v);
    const int lane = threadIdx.x & 63, wv = threadIdx.x >> 6;
    if (lane == 0) wr[wv] = v;
    __syncthreads();
    float r = wr[0];
#pragma unroll
    for (int i = 1; i < NW; ++i) r = fmaxf(r, wr[i]);
    __syncthreads();
    return r;
}
template <int NW>
DI float blockSum(float v, float* wr) {
    v = bflySum(v);
    const int lane = threadIdx.x & 63, wv = threadIdx.x >> 6;
    if (lane == 0) wr[wv] = v;
    __syncthreads();
    float r = wr[0];
#pragma unroll
    for (int i = 1; i < NW; ++i) r += wr[i];
    __syncthreads();
    return r;
}

// ---------------- precompute kernels ----------------

// log_softmax of prior_logits (S) -> prior_ls
__global__ __launch_bounds__(512) void k_prior(const float* __restrict__ pl,
                                               float* __restrict__ prior_ls) {
    __shared__ float wr[8];
    const int s = threadIdx.x;
    float x = pl[s];
    float m = blockMax<8>(x, wr);
    float e = __expf(x - m);
    float sum = blockSum<8>(e, wr);
    prior_ls[s] = x - m - __logf(sum);
}

// softmax rows of trans_logits (A*S rows of S) -> P (probabilities, fp32)
__global__ __launch_bounds__(256) void k_trans(const float* __restrict__ tl,
                                               float* __restrict__ P) {
    __shared__ float wr[4];
    const size_t row = blockIdx.x;
    const float* in = tl + row * SS;
    const int tid = threadIdx.x;
    float x0 = in[tid];
    float x1 = in[tid + 256];
    float m = blockMax<4>(fmaxf(x0, x1), wr);
    float e0 = __expf(x0 - m);
    float e1 = __expf(x1 - m);
    float sum = blockSum<4>(e0 + e1, wr);
    float inv = 1.0f / sum;
    float* o = P + row * SS;
    o[tid] = e0 * inv;
    o[tid + 256] = e1 * inv;
}

// per-row (s) max and log-sum-exp of obs_logits (S x O) -> mo, lo
__global__ __launch_bounds__(256) void k_obs_stats(const float* __restrict__ ol,
                                                   float* __restrict__ mo,
                                                   float* __restrict__ lo) {
    __shared__ float wr[4];
    const int s = blockIdx.x;
    const float* in = ol + (size_t)s * OO;
    const int tid = threadIdx.x;
    float mx = -INFINITY;
    for (int i = tid; i < OO; i += 256) mx = fmaxf(mx, in[i]);
    float m = blockMax<4>(mx, wr);
    float sm = 0.f;
    for (int i = tid; i < OO; i += 256) sm += __expf(in[i] - m);
    float sum = blockSum<4>(sm, wr);
    if (tid == 0) { mo[s] = m; lo[s] = __logf(sum); }
}

// transposed log_softmax: obsT[o][s] = obs_logits[s][o] - mo[s] - lo[s]
// grid: (OO/64) * (SS/64) blocks of 256 threads, 64x64 LDS tile
__global__ __launch_bounds__(256) void k_obsT(const float* __restrict__ ol,
                                              const float* __restrict__ mo,
                                              const float* __restrict__ lo,
                                              float* __restrict__ obsT) {
    __shared__ float tile[64][65];
    const int tO = blockIdx.x % (OO / 64);
    const int tS = blockIdx.x / (OO / 64);
    const int o0 = tO * 64, s0 = tS * 64;
    const int cc = threadIdx.x & 63, rr = threadIdx.x >> 6;  // rr in 0..3
#pragma unroll
    for (int j = 0; j < 16; ++j) {
        int r = rr + j * 4;  // s offset within tile
        tile[r][cc] = ol[(size_t)(s0 + r) * OO + o0 + cc] - mo[s0 + r] - lo[s0 + r];
    }
    __syncthreads();
#pragma unroll
    for (int j = 0; j < 16; ++j) {
        int r = rr + j * 4;  // o offset within tile
        obsT[(size_t)(o0 + r) * SS + s0 + cc] = tile[cc][r];
    }
}

// transposed log_softmax of policy_logits (S x A) -> polT[a][s]
__global__ __launch_bounds__(512) void k_polT(const float* __restrict__ pol,
                                              float* __restrict__ polT) {
    const int s = threadIdx.x;
    const float* row = pol + (size_t)s * AA;
    float x[AA];
    float m = -INFINITY;
#pragma unroll
    for (int a = 0; a < AA; ++a) { x[a] = row[a]; m = fmaxf(m, x[a]); }
    float sum = 0.f;
#pragma unroll
    for (int a = 0; a < AA; ++a) sum += __expf(x[a] - m);
    float ls = m + __logf(sum);
#pragma unroll
    for (int a = 0; a < AA; ++a) polT[a * SS + s] = x[a] - ls;
}

// ---------------- main sequential-scan kernel ----------------
// one block per batch element, 512 threads (one per state)
__global__ __launch_bounds__(512) void k_main(
    const float* __restrict__ regime, const int* __restrict__ obs,
    const float* __restrict__ rewards, const float* __restrict__ dones,
    const int* __restrict__ actions, const float* __restrict__ prior_ls,
    const float* __restrict__ P, const float* __restrict__ obsT,
    const float* __restrict__ polT, const float* __restrict__ r_mu,
    const float* __restrict__ r_logsig, float* __restrict__ out) {
    __shared__ float wr[8];
    __shared__ float p_lds[SS];
    __shared__ float lqprev[SS];
    __shared__ float4 red4[SS];

    const int b = blockIdx.x;
    const int tid = threadIdx.x;
    const int s = tid;
    const int c = tid & 127;   // column group (4 columns per thread)
    const int sg = tid >> 7;   // s-range group (0..3), uniform within a wave

    const float rm = r_mu[s];
    const float rls = r_logsig[s];
    const float inv_sig = __expf(-rls);
    const float reg = regime[b];

    float log_prob = 0.f;
    float was_done = 0.f;

    for (int t = 0; t <= TT; ++t) {
        const int o = obs[t * BB + b];
        const float r = rewards[t * BB + b];
        float diff = (r - rm) * inv_sig;
        float emis = obsT[(size_t)o * SS + s] + (-0.5f * diff * diff - rls - 0.5f * LOG2PI);

        float base_in = (t == 0) ? prior_ls[s] : lqprev[s];

        float done = was_done;
        int a = 0;
        float la = 0.f;
        if (t < TT) {
            a = actions[t * BB + b];
            float d = dones[t * BB + b];
            done = fmaxf(was_done, d);
            la = polT[a * SS + s];
            if (done == 1.0f || reg == 1.0f) la = 0.f;
        }
        float lq = base_in + emis + la;

        // lse over s
        float m = blockMax<8>(lq, wr);
        float ex = __expf(lq - m);   // p[s] * exp(m') scaling handled via base
        p_lds[s] = ex;               // visible after blockSum's syncthreads
        float sum = blockSum<8>(ex, wr);
        float lse = m + __logf(sum);
        float lq_orda = lse * (1.0f - was_done);
        if (!isinf(log_prob)) log_prob += lq_orda;

        if (t == TT) break;
        was_done = done;

        // lq_snext[s'] = (m - lq_orda) + log( sum_s exp(lq[s]-m) * P[a][s][s'] )
        const float base = m - lq_orda;
        const float* Pa = P + (size_t)a * SS * SS;
        const float4* pr = (const float4*)(Pa + (size_t)(sg * 128) * SS) + c;
        float ax = 0.f, ay = 0.f, az = 0.f, aw = 0.f;
#pragma unroll 4
        for (int si = 0; si < 128; ++si) {
            float ps = p_lds[(sg << 7) + si];   // wave-uniform broadcast
            float4 row = pr[(size_t)si * (SS / 4)];
            ax = fmaf(ps, row.x, ax);
            ay = fmaf(ps, row.y, ay);
            az = fmaf(ps, row.z, az);
            aw = fmaf(ps, row.w, aw);
        }
        red4[tid] = make_float4(ax, ay, az, aw);
        __syncthreads();
        if (sg == 0) {  // tid == c in 0..127
            float4 a0 = red4[c];
            float4 a1 = red4[c + 128];
            float4 a2 = red4[c + 256];
            float4 a3 = red4[c + 384];
            float tx = a0.x + a1.x + a2.x + a3.x;
            float ty = a0.y + a1.y + a2.y + a3.y;
            float tz = a0.z + a1.z + a2.z + a3.z;
            float tw = a0.w + a1.w + a2.w + a3.w;
            lqprev[4 * c + 0] = base + __logf(tx);
            lqprev[4 * c + 1] = base + __logf(ty);
            lqprev[4 * c + 2] = base + __logf(tz);
            lqprev[4 * c + 3] = base + __logf(tw);
        }
        __syncthreads();
    }

    if (tid == 0) out[b] = log_prob;
}

// ---------------- launch ----------------
extern "C" void kernel_launch(void* const* d_in, const int* in_sizes, int n_in,
                              void* d_out, int out_size, void* d_ws, size_t ws_size,
                              hipStream_t stream) {
    const float* regime = (const float*)d_in[0];
    const int* obs = (const int*)d_in[1];
    const float* rewards = (const float*)d_in[2];
    const float* dones = (const float*)d_in[3];
    const int* actions = (const int*)d_in[4];
    const float* prior_logits = (const float*)d_in[5];
    const float* trans_logits = (const float*)d_in[6];
    const float* obs_logits = (const float*)d_in[7];
    const float* policy_logits = (const float*)d_in[8];
    const float* r_mu = (const float*)d_in[9];
    const float* r_logsig = (const float*)d_in[10];
    float* out = (float*)d_out;

    char* ws = (char*)d_ws;
    float* P = (float*)ws;                                         // A*S*S fp32 = 16 MB
    float* obsT = (float*)(ws + (size_t)AA * SS * SS * 4);         // O*S fp32 = 8 MB
    float* prior_ls = (float*)(ws + (size_t)(AA * SS * SS + (size_t)OO * SS) * 4);
    float* polT = prior_ls + SS;                                   // A*S
    float* mo = polT + AA * SS;                                    // S
    float* lo = mo + SS;                                           // S

    k_prior<<<1, 512, 0, stream>>>(prior_logits, prior_ls);
    k_trans<<<AA * SS, 256, 0, stream>>>(trans_logits, P);
    k_obs_stats<<<SS, 256, 0, stream>>>(obs_logits, mo, lo);
    k_obsT<<<(OO / 64) * (SS / 64), 256, 0, stream>>>(obs_logits, mo, lo, obsT);
    k_polT<<<1, 512, 0, stream>>>(policy_logits, polT);
    k_main<<<BB, 512, 0, stream>>>(regime, obs, rewards, dones, actions, prior_ls,
                                   P, obsT, polT, r_mu, r_logsig, out);
}

// Round 2
// 975.367 us; speedup vs baseline: 1.7375x; 1.7375x over previous
//
#include <hip/hip_runtime.h>
#include <hip/hip_fp16.h>
#include <math.h>

#define DI __device__ __forceinline__

constexpr int BB = 64;     // batch
constexpr int TT = 128;    // action steps (obs/rewards have TT+1)
constexpr int SS = 512;    // states
constexpr int AA = 16;     // actions
constexpr int OO = 4096;   // observations
constexpr float LOG2PI = 1.8378770664093453f;

// ---------------- reduction helpers (wave64) ----------------
DI float bflyMax(float v) {
#pragma unroll
    for (int off = 32; off; off >>= 1) v = fmaxf(v, __shfl_xor(v, off));
    return v;
}
DI float bflySum(float v) {
#pragma unroll
    for (int off = 32; off; off >>= 1) v += __shfl_xor(v, off);
    return v;
}

template <int NW>
DI float blockMax(float v, float* wr) {
    v = bflyMax(v);
    const int lane = threadIdx.x & 63, wv = threadIdx.x >> 6;
    if (lane == 0) wr[wv] = v;
    __syncthreads();
    float r = wr[0];
#pragma unroll
    for (int i = 1; i < NW; ++i) r = fmaxf(r, wr[i]);
    __syncthreads();
    return r;
}
template <int NW>
DI float blockSum(float v, float* wr) {
    v = bflySum(v);
    const int lane = threadIdx.x & 63, wv = threadIdx.x >> 6;
    if (lane == 0) wr[wv] = v;
    __syncthreads();
    float r = wr[0];
#pragma unroll
    for (int i = 1; i < NW; ++i) r += wr[i];
    __syncthreads();
    return r;
}

// ---------------- precompute kernels ----------------

__global__ __launch_bounds__(512) void k_prior(const float* __restrict__ pl,
                                               float* __restrict__ prior_ls) {
    __shared__ float wr[8];
    const int s = threadIdx.x;
    float x = pl[s];
    float m = blockMax<8>(x, wr);
    float e = __expf(x - m);
    float sum = blockSum<8>(e, wr);
    prior_ls[s] = x - m - __logf(sum);
}

// softmax rows of trans_logits (A*S rows of S) -> P (probabilities, fp16)
__global__ __launch_bounds__(256) void k_trans(const float* __restrict__ tl,
                                               __half* __restrict__ P) {
    __shared__ float wr[4];
    const size_t row = blockIdx.x;
    const float* in = tl + row * SS;
    const int tid = threadIdx.x;
    float x0 = in[tid];
    float x1 = in[tid + 256];
    float m = blockMax<4>(fmaxf(x0, x1), wr);
    float e0 = __expf(x0 - m);
    float e1 = __expf(x1 - m);
    float sum = blockSum<4>(e0 + e1, wr);
    float inv = 1.0f / sum;
    __half* o = P + row * SS;
    o[tid] = __float2half(e0 * inv);
    o[tid + 256] = __float2half(e1 * inv);
}

__global__ __launch_bounds__(256) void k_obs_stats(const float* __restrict__ ol,
                                                   float* __restrict__ mo,
                                                   float* __restrict__ lo) {
    __shared__ float wr[4];
    const int s = blockIdx.x;
    const float* in = ol + (size_t)s * OO;
    const int tid = threadIdx.x;
    float mx = -INFINITY;
    for (int i = tid; i < OO; i += 256) mx = fmaxf(mx, in[i]);
    float m = blockMax<4>(mx, wr);
    float sm = 0.f;
    for (int i = tid; i < OO; i += 256) sm += __expf(in[i] - m);
    float sum = blockSum<4>(sm, wr);
    if (tid == 0) { mo[s] = m; lo[s] = __logf(sum); }
}

__global__ __launch_bounds__(256) void k_obsT(const float* __restrict__ ol,
                                              const float* __restrict__ mo,
                                              const float* __restrict__ lo,
                                              float* __restrict__ obsT) {
    __shared__ float tile[64][65];
    const int tO = blockIdx.x % (OO / 64);
    const int tS = blockIdx.x / (OO / 64);
    const int o0 = tO * 64, s0 = tS * 64;
    const int cc = threadIdx.x & 63, rr = threadIdx.x >> 6;
#pragma unroll
    for (int j = 0; j < 16; ++j) {
        int r = rr + j * 4;
        tile[r][cc] = ol[(size_t)(s0 + r) * OO + o0 + cc] - mo[s0 + r] - lo[s0 + r];
    }
    __syncthreads();
#pragma unroll
    for (int j = 0; j < 16; ++j) {
        int r = rr + j * 4;
        obsT[(size_t)(o0 + r) * SS + s0 + cc] = tile[cc][r];
    }
}

__global__ __launch_bounds__(512) void k_polT(const float* __restrict__ pol,
                                              float* __restrict__ polT) {
    const int s = threadIdx.x;
    const float* row = pol + (size_t)s * AA;
    float x[AA];
    float m = -INFINITY;
#pragma unroll
    for (int a = 0; a < AA; ++a) { x[a] = row[a]; m = fmaxf(m, x[a]); }
    float sum = 0.f;
#pragma unroll
    for (int a = 0; a < AA; ++a) sum += __expf(x[a] - m);
    float ls = m + __logf(sum);
#pragma unroll
    for (int a = 0; a < AA; ++a) polT[a * SS + s] = x[a] - ls;
}

// ---------------- main sequential-scan kernel ----------------
// one block per batch element, 1024 threads (16 waves).
// Phase A (threads 0..511): per-state lq, block lse.
// Phase B (all 16 waves): GEMV lq_snext = log(p . P[a]) with fp16 P.
//   wave w owns rows s in [32w, 32w+32); thread owns 8 contiguous columns
//   c = (lane*8 .. lane*8+8)  -> float4 loads of 8 halves, fully coalesced
//   (one wave instruction = one full 1KB row of P[a]).
constexpr int NW_MAIN = 16;

__global__ __launch_bounds__(1024) void k_main(
    const float* __restrict__ regime, const int* __restrict__ obs,
    const float* __restrict__ rewards, const float* __restrict__ dones,
    const int* __restrict__ actions, const float* __restrict__ prior_ls,
    const __half* __restrict__ Ph, const float* __restrict__ obsT,
    const float* __restrict__ polT, const float* __restrict__ r_mu,
    const float* __restrict__ r_logsig, float* __restrict__ out) {
    __shared__ float wr[NW_MAIN];
    __shared__ float p_lds[SS];
    __shared__ float lqprev[SS];
    __shared__ float red[NW_MAIN * SS];  // 32 KB

    const int b = blockIdx.x;
    const int tid = threadIdx.x;
    const int wv = tid >> 6, lane = tid & 63;
    const int s = tid;  // valid state if < SS

    float rm = 0.f, rls = 0.f, inv_sig = 1.f;
    if (s < SS) {
        rm = r_mu[s];
        rls = r_logsig[s];
        inv_sig = __expf(-rls);
    }
    const float reg = regime[b];

    float log_prob = 0.f;
    float was_done = 0.f;

    for (int t = 0; t <= TT; ++t) {
        const int o = obs[t * BB + b];
        const float r = rewards[t * BB + b];
        int a = 0;
        float d = 0.f;
        if (t < TT) {
            a = actions[t * BB + b];
            d = dones[t * BB + b];
        }
        const float done = fmaxf(was_done, d);

        float lq = -INFINITY;
        if (s < SS) {
            float diff = (r - rm) * inv_sig;
            float emis = obsT[(size_t)o * SS + s] - 0.5f * diff * diff - rls - 0.5f * LOG2PI;
            float base_in = (t == 0) ? prior_ls[s] : lqprev[s];
            float la = 0.f;
            if (t < TT) {
                la = polT[a * SS + s];
                if (done == 1.0f || reg == 1.0f) la = 0.f;
            }
            lq = base_in + emis + la;
        }

        float m = blockMax<NW_MAIN>(lq, wr);
        float ex = (s < SS) ? __expf(lq - m) : 0.f;
        if (s < SS) p_lds[s] = ex;  // published by blockSum's barriers
        float sum = blockSum<NW_MAIN>(ex, wr);
        float lse = m + __logf(sum);
        float lq_orda = lse * (1.0f - was_done);
        if (!isinf(log_prob)) log_prob += lq_orda;

        if (t == TT) break;
        was_done = done;

        // GEMV: lq_snext[c] = (m - lq_orda) + log( sum_s p[s] * P[a][s][c] )
        const float basev = m - lq_orda;
        const float4* Pa4 = (const float4*)(Ph + (size_t)a * SS * SS);  // 8 halves per float4
        const int s0 = wv * 32;
        float acc[8];
#pragma unroll
        for (int j = 0; j < 8; ++j) acc[j] = 0.f;
#pragma unroll 8
        for (int i = 0; i < 32; ++i) {
            const float ps = p_lds[s0 + i];  // wave-uniform broadcast
            float4 raw = Pa4[(size_t)(s0 + i) * (SS / 8) + lane];
            const __half2* h2 = (const __half2*)&raw;
#pragma unroll
            for (int j = 0; j < 4; ++j) {
                acc[2 * j] = fmaf(ps, __low2float(h2[j]), acc[2 * j]);
                acc[2 * j + 1] = fmaf(ps, __high2float(h2[j]), acc[2 * j + 1]);
            }
        }
        float4* myred = (float4*)(red + wv * SS + lane * 8);
        myred[0] = make_float4(acc[0], acc[1], acc[2], acc[3]);
        myred[1] = make_float4(acc[4], acc[5], acc[6], acc[7]);
        __syncthreads();
        if (s < SS) {
            float tot = 0.f;
#pragma unroll
            for (int w = 0; w < NW_MAIN; ++w) tot += red[w * SS + s];
            lqprev[s] = basev + __logf(tot);
        }
        __syncthreads();
    }

    if (tid == 0) out[b] = log_prob;
}

// ---------------- launch ----------------
extern "C" void kernel_launch(void* const* d_in, const int* in_sizes, int n_in,
                              void* d_out, int out_size, void* d_ws, size_t ws_size,
                              hipStream_t stream) {
    const float* regime = (const float*)d_in[0];
    const int* obs = (const int*)d_in[1];
    const float* rewards = (const float*)d_in[2];
    const float* dones = (const float*)d_in[3];
    const int* actions = (const int*)d_in[4];
    const float* prior_logits = (const float*)d_in[5];
    const float* trans_logits = (const float*)d_in[6];
    const float* obs_logits = (const float*)d_in[7];
    const float* policy_logits = (const float*)d_in[8];
    const float* r_mu = (const float*)d_in[9];
    const float* r_logsig = (const float*)d_in[10];
    float* out = (float*)d_out;

    char* ws = (char*)d_ws;
    __half* Ph = (__half*)ws;                                   // A*S*S fp16 = 8 MB
    float* obsT = (float*)(ws + (size_t)AA * SS * SS * 2);      // O*S fp32 = 8 MB
    float* prior_ls = (float*)(ws + (size_t)AA * SS * SS * 2 + (size_t)OO * SS * 4);
    float* polT = prior_ls + SS;                                // A*S
    float* mo = polT + AA * SS;                                 // S
    float* lo = mo + SS;                                        // S

    k_prior<<<1, 512, 0, stream>>>(prior_logits, prior_ls);
    k_trans<<<AA * SS, 256, 0, stream>>>(trans_logits, Ph);
    k_obs_stats<<<SS, 256, 0, stream>>>(obs_logits, mo, lo);
    k_obsT<<<(OO / 64) * (SS / 64), 256, 0, stream>>>(obs_logits, mo, lo, obsT);
    k_polT<<<1, 512, 0, stream>>>(policy_logits, polT);
    k_main<<<BB, 1024, 0, stream>>>(regime, obs, rewards, dones, actions, prior_ls,
                                    Ph, obsT, polT, r_mu, r_logsig, out);
}

// Round 3
// 648.961 us; speedup vs baseline: 2.6114x; 1.5030x over previous
//
#include <hip/hip_runtime.h>
#include <math.h>

#define DI __device__ __forceinline__

constexpr int BB = 64;     // batch
constexpr int TT = 128;    // action steps (obs/rewards have TT+1)
constexpr int SS = 512;    // states
constexpr int AA = 16;     // actions
constexpr int OO = 4096;   // observations
constexpr float LOG2PI = 1.8378770664093453f;
constexpr float LOG4096 = 8.317766166719343f;  // log(16*256)

typedef float f32x4 __attribute__((ext_vector_type(4)));

// ---------------- fp8 e4m3fn converter (RTNE), x in [0, 448) ----------------
DI unsigned int f32_to_e4m3(float x) {
    unsigned int u = __float_as_uint(x);
    unsigned int lsb = (u >> 20) & 1u;
    unsigned int rounded = u + 0x7ffffu + lsb;          // RTNE into 3-bit mantissa
    int e8 = (int)(rounded >> 23) - 120;                // 127 - 7
    unsigned int m3 = (rounded >> 20) & 7u;
    unsigned int norm = ((unsigned int)e8 << 3) | m3;
    int sub = __float2int_rn(x * 512.0f);               // subnormal: multiples of 2^-9
    return (e8 <= 0) ? (unsigned int)sub : norm;
}

// ---------------- reduction helpers (wave64) ----------------
DI float bflyMax(float v) {
#pragma unroll
    for (int off = 32; off; off >>= 1) v = fmaxf(v, __shfl_xor(v, off));
    return v;
}
DI float bflySum(float v) {
#pragma unroll
    for (int off = 32; off; off >>= 1) v += __shfl_xor(v, off);
    return v;
}
// half-wave (32-lane) reductions: stay within 32-aligned half
DI float halfMax(float v) {
#pragma unroll
    for (int off = 16; off; off >>= 1) v = fmaxf(v, __shfl_xor(v, off));
    return v;
}
DI float halfSum(float v) {
#pragma unroll
    for (int off = 16; off; off >>= 1) v += __shfl_xor(v, off);
    return v;
}

template <int NW>
DI float blockMax(float v, float* wr) {
    v = bflyMax(v);
    const int lane = threadIdx.x & 63, wv = threadIdx.x >> 6;
    if (lane == 0) wr[wv] = v;
    __syncthreads();
    float r = wr[0];
#pragma unroll
    for (int i = 1; i < NW; ++i) r = fmaxf(r, wr[i]);
    __syncthreads();
    return r;
}
template <int NW>
DI float blockSum(float v, float* wr) {
    v = bflySum(v);
    const int lane = threadIdx.x & 63, wv = threadIdx.x >> 6;
    if (lane == 0) wr[wv] = v;
    __syncthreads();
    float r = wr[0];
#pragma unroll
    for (int i = 1; i < NW; ++i) r += wr[i];
    __syncthreads();
    return r;
}

// ---------------- precompute kernels ----------------

__global__ __launch_bounds__(512) void k_prior(const float* __restrict__ pl,
                                               float* __restrict__ prior_ls) {
    __shared__ float wr[8];
    const int s = threadIdx.x;
    float x = pl[s];
    float m = blockMax<8>(x, wr);
    float e = __expf(x - m);
    float sum = blockSum<8>(e, wr);
    prior_ls[s] = x - m - __logf(sum);
}

// Fused softmax + fp8 quantize (x256) + MFMA-B-fragment swizzle.
// grid: 256 blocks = (a in 0..15) x (kt in 0..15); 1024 threads.
// thread: r = tid>>5 (row within ktile, 0..31), nt = tid&31 (16-col tile).
// Output layout (per (a,kt) 16KB region): ntp (=nt>>1) * 1024 + lane*16 + (nt&1)*8 + j
//   where lane = (r>>3)*16 + i  (i = col within tile), j = r&7.
// Main kernel reads ulonglong2 at ((kt*16+ntp)*64 + lane)*16: .x = frag(tile 2ntp),
// .y = frag(tile 2ntp+1); byte j of frag = P[a][kt*32 + (lane>>4)*8 + j][nt*16 + (lane&15)]*256.
__global__ __launch_bounds__(1024) void k_pack(const float* __restrict__ tl,
                                               unsigned char* __restrict__ PB) {
    __shared__ unsigned char lds[16384];
    const int a = blockIdx.x >> 4;
    const int kt = blockIdx.x & 15;
    const int tid = threadIdx.x;
    const int r = tid >> 5;       // 0..31
    const int nt = tid & 31;      // 0..31
    const int k = kt * 32 + r;
    const float* row = tl + ((size_t)a * SS + k) * SS + nt * 16;

    float x[16];
#pragma unroll
    for (int i = 0; i < 4; ++i) {
        float4 v = ((const float4*)row)[i];
        x[4 * i] = v.x; x[4 * i + 1] = v.y; x[4 * i + 2] = v.z; x[4 * i + 3] = v.w;
    }
    float mx = -INFINITY;
#pragma unroll
    for (int i = 0; i < 16; ++i) mx = fmaxf(mx, x[i]);
    mx = halfMax(mx);   // row lives in one 32-lane half
    float e[16];
    float sm = 0.f;
#pragma unroll
    for (int i = 0; i < 16; ++i) { e[i] = __expf(x[i] - mx); sm += e[i]; }
    sm = halfSum(sm);
    const float scale = 256.0f / sm;

    const int base = (nt >> 1) * 1024 + ((r >> 3) * 16) * 16 + (nt & 1) * 8 + (r & 7);
#pragma unroll
    for (int i = 0; i < 16; ++i) {
        lds[base + i * 16] = (unsigned char)f32_to_e4m3(e[i] * scale);
    }
    __syncthreads();

    ulonglong2* dst = (ulonglong2*)(PB + (size_t)(a * 16 + kt) * 16384);
    dst[tid] = ((const ulonglong2*)lds)[tid];
}

__global__ __launch_bounds__(256) void k_obs_stats(const float* __restrict__ ol,
                                                   float* __restrict__ mo,
                                                   float* __restrict__ lo) {
    __shared__ float wr[4];
    const int s = blockIdx.x;
    const float* in = ol + (size_t)s * OO;
    const int tid = threadIdx.x;
    float mx = -INFINITY;
    for (int i = tid; i < OO; i += 256) mx = fmaxf(mx, in[i]);
    float m = blockMax<4>(mx, wr);
    float sm = 0.f;
    for (int i = tid; i < OO; i += 256) sm += __expf(in[i] - m);
    float sum = blockSum<4>(sm, wr);
    if (tid == 0) { mo[s] = m; lo[s] = __logf(sum); }
}

__global__ __launch_bounds__(256) void k_obsT(const float* __restrict__ ol,
                                              const float* __restrict__ mo,
                                              const float* __restrict__ lo,
                                              float* __restrict__ obsT) {
    __shared__ float tile[64][65];
    const int tO = blockIdx.x % (OO / 64);
    const int tS = blockIdx.x / (OO / 64);
    const int o0 = tO * 64, s0 = tS * 64;
    const int cc = threadIdx.x & 63, rr = threadIdx.x >> 6;
#pragma unroll
    for (int j = 0; j < 16; ++j) {
        int r = rr + j * 4;
        tile[r][cc] = ol[(size_t)(s0 + r) * OO + o0 + cc] - mo[s0 + r] - lo[s0 + r];
    }
    __syncthreads();
#pragma unroll
    for (int j = 0; j < 16; ++j) {
        int r = rr + j * 4;
        obsT[(size_t)(o0 + r) * SS + s0 + cc] = tile[cc][r];
    }
}

__global__ __launch_bounds__(512) void k_polT(const float* __restrict__ pol,
                                              float* __restrict__ polT) {
    const int s = threadIdx.x;
    const float* row = pol + (size_t)s * AA;
    float x[AA];
    float m = -INFINITY;
#pragma unroll
    for (int a = 0; a < AA; ++a) { x[a] = row[a]; m = fmaxf(m, x[a]); }
    float sum = 0.f;
#pragma unroll
    for (int a = 0; a < AA; ++a) sum += __expf(x[a] - m);
    float ls = m + __logf(sum);
#pragma unroll
    for (int a = 0; a < AA; ++a) polT[a * SS + s] = x[a] - ls;
}

// ---------------- main sequential-scan kernel ----------------
// one block per batch element, 1024 threads = 16 waves.
// Per step: phase A computes lq[s] (threads 0..511), block lse; p quantized to
// fp8 (x16) into LDS; phase B: each wave w owns ntile pair (2w, 2w+1) and runs
// 16 k-tile fp8 MFMAs per ntile, B-fragments loaded straight from the
// pre-swizzled PB (one dwordx4 per lane covers both ntiles of the pair).
constexpr int NW_MAIN = 16;

__global__ __launch_bounds__(1024) void k_main(
    const float* __restrict__ regime, const int* __restrict__ obs,
    const float* __restrict__ rewards, const float* __restrict__ dones,
    const int* __restrict__ actions, const float* __restrict__ prior_ls,
    const unsigned char* __restrict__ PB, const float* __restrict__ obsT,
    const float* __restrict__ polT, const float* __restrict__ r_mu,
    const float* __restrict__ r_logsig, float* __restrict__ out) {
    __shared__ float wr[NW_MAIN];
    __shared__ unsigned long long p8q[64];   // 512 fp8 bytes of p*16
    __shared__ float lqprev[SS];

    const int b = blockIdx.x;
    const int tid = threadIdx.x;
    const int wv = tid >> 6, lane = tid & 63;
    const int quad = lane >> 4;
    const int s = tid;

    float rm = 0.f, rls = 0.f, inv_sig = 1.f;
    if (s < SS) {
        rm = r_mu[s];
        rls = r_logsig[s];
        inv_sig = __expf(-rls);
    }
    const float reg = regime[b];

    float log_prob = 0.f;
    float was_done = 0.f;

    for (int t = 0; t <= TT; ++t) {
        const int o = obs[t * BB + b];
        const float r = rewards[t * BB + b];
        int a = 0;
        float d = 0.f;
        if (t < TT) {
            a = actions[t * BB + b];
            d = dones[t * BB + b];
        }
        const float done = fmaxf(was_done, d);

        float lq = -INFINITY;
        if (s < SS) {
            float diff = (r - rm) * inv_sig;
            float emis = obsT[(size_t)o * SS + s] - 0.5f * diff * diff - rls - 0.5f * LOG2PI;
            float base_in = (t == 0) ? prior_ls[s] : lqprev[s];
            float la = 0.f;
            if (t < TT) {
                la = polT[a * SS + s];
                if (done == 1.0f || reg == 1.0f) la = 0.f;
            }
            lq = base_in + emis + la;
        }

        float m = blockMax<NW_MAIN>(lq, wr);
        float ex = (s < SS) ? __expf(lq - m) : 0.f;
        if (s < SS) {
            ((unsigned char*)p8q)[s] = (unsigned char)f32_to_e4m3(ex * 16.0f);
        }
        float sum = blockSum<NW_MAIN>(ex, wr);   // barriers also publish p8q
        float lse = m + __logf(sum);
        float lq_orda = lse * (1.0f - was_done);
        if (!isinf(log_prob)) log_prob += lq_orda;

        if (t == TT) break;
        was_done = done;

        // lq_next[n] = (m - lq_orda) + log( sum_s p~[s] * P~[a][s][n] ) - log(4096)
        const float basev = m - lq_orda - LOG4096;
        const ulonglong2* PBa = (const ulonglong2*)(PB + (size_t)a * (16 * 16384));
        f32x4 acc0 = {0.f, 0.f, 0.f, 0.f};
        f32x4 acc1 = {0.f, 0.f, 0.f, 0.f};
#pragma unroll
        for (int kt = 0; kt < 16; ++kt) {
            long afrag = (long)p8q[kt * 4 + quad];              // LDS broadcast per quad
            ulonglong2 bf = PBa[(kt * 16 + wv) * 64 + lane];    // coalesced dwordx4
            acc0 = __builtin_amdgcn_mfma_f32_16x16x32_fp8_fp8((long)bf.x, afrag, acc0, 0, 0, 0);
            acc1 = __builtin_amdgcn_mfma_f32_16x16x32_fp8_fp8((long)bf.y, afrag, acc1, 0, 0, 0);
        }
        // NOTE operand order: D = A*B with A = B-fragment-of-PB? MFMA computes
        // D[m][n] with first operand = A (m-indexed), second = B (n-indexed).
        // We pass (Pfrag, pfrag): then A = P-fragment (its lane&15 index = our
        // column n), B = p-fragment (all "columns" identical). D[m][n]:
        // m = our column (lane&15 of D), n = any. Either assignment works
        // because p's fragment is constant across its 16-index; D col=lane&15
        // picks our P column via A's m when P is first operand... With
        // symmetric construction (one operand constant across its free index),
        // D[lane&15] = sum_k p[k]*P[k][col] for col = lane&15 in both cases.
        if (lane < 16) {
            lqprev[wv * 32 + lane] = basev + __logf(acc0[0]);
            lqprev[wv * 32 + 16 + lane] = basev + __logf(acc1[0]);
        }
        __syncthreads();
    }

    if (tid == 0) out[b] = log_prob;
}

// ---------------- launch ----------------
extern "C" void kernel_launch(void* const* d_in, const int* in_sizes, int n_in,
                              void* d_out, int out_size, void* d_ws, size_t ws_size,
                              hipStream_t stream) {
    const float* regime = (const float*)d_in[0];
    const int* obs = (const int*)d_in[1];
    const float* rewards = (const float*)d_in[2];
    const float* dones = (const float*)d_in[3];
    const int* actions = (const int*)d_in[4];
    const float* prior_logits = (const float*)d_in[5];
    const float* trans_logits = (const float*)d_in[6];
    const float* obs_logits = (const float*)d_in[7];
    const float* policy_logits = (const float*)d_in[8];
    const float* r_mu = (const float*)d_in[9];
    const float* r_logsig = (const float*)d_in[10];
    float* out = (float*)d_out;

    char* ws = (char*)d_ws;
    unsigned char* PB = (unsigned char*)ws;                    // A*S*S fp8 = 4 MB
    float* obsT = (float*)(ws + (size_t)AA * SS * SS);         // O*S fp32 = 8 MB
    float* prior_ls = (float*)(ws + (size_t)AA * SS * SS + (size_t)OO * SS * 4);
    float* polT = prior_ls + SS;                               // A*S
    float* mo = polT + AA * SS;                                // S
    float* lo = mo + SS;                                       // S

    k_prior<<<1, 512, 0, stream>>>(prior_logits, prior_ls);
    k_pack<<<256, 1024, 0, stream>>>(trans_logits, PB);
    k_obs_stats<<<SS, 256, 0, stream>>>(obs_logits, mo, lo);
    k_obsT<<<(OO / 64) * (SS / 64), 256, 0, stream>>>(obs_logits, mo, lo, obsT);
    k_polT<<<1, 512, 0, stream>>>(policy_logits, polT);
    k_main<<<BB, 1024, 0, stream>>>(regime, obs, rewards, dones, actions, prior_ls,
                                    PB, obsT, polT, r_mu, r_logsig, out);
}